// Round 19
// baseline (55.832 us; speedup 1.0000x reference)
//
#include <hip/hip_runtime.h>

// ---------------------------------------------------------------------------
// UpThreeOffsetsConvShareWeights v19 (resubmit; r18 was an infra failure).
//
// Algebra unchanged (separable deform offsets -> per-phase 2x2x2-tap conv ==
// GEMM M=spatial x N=96 x K=512; fused K=96 combine GEMM), C^T convention,
// 32x32x16 MFMA, v5-proven W_sw/W2_sw layouts, v7-proven xT2 4-region
// x-from-L2 (zero-tail OOB), v16 zero-sync loop + v17 x ping-pong + v18
// coalesced prep writes and setprio.
//
// v18 post-mortem: total 53.98 (plateau with v12's 52.65); MfmaUtil 23%,
// no pipe >25%. Last mechanism-backed lever: the prologue waits on the FULL
// 96KB phase-weight stage before tap 0 (x2 rounds/CU). v19 splits it:
//   stage taps 0-3 (48KB) -> sync -> issue taps 4-7 stage -> compute taps
//   0-3 (~4700cy MFMA cover >> 48KB stage time) -> vmcnt(0)+barrier ->
//   taps 4-7. Exposed stage wait halves; 2 barriers total.
// ---------------------------------------------------------------------------

typedef __bf16 bf16x8 __attribute__((ext_vector_type(8)));
typedef float f32x16 __attribute__((ext_vector_type(16)));
typedef unsigned u32x2 __attribute__((ext_vector_type(2)));

__device__ inline unsigned short f2bf(float f) {
  unsigned int u = __float_as_uint(f);
  u += 0x7FFFu + ((u >> 16) & 1u);
  return (unsigned short)(u >> 16);
}

__device__ inline bf16x8 bc16(uint4 v) { return __builtin_bit_cast(bf16x8, v); }

__device__ inline unsigned cvtpk(float lo, float hi) {
  unsigned r;
  asm("v_cvt_pk_bf16_f32 %0, %1, %2" : "=v"(r) : "v"(lo), "v"(hi));
  return r;
}

__device__ inline void plswap(unsigned& a, unsigned& b) {
  u32x2 r = __builtin_amdgcn_permlane32_swap(a, b, false, false);
  a = r.x;
  b = r.y;
}

__device__ inline void gload16(const unsigned short* g, unsigned short* l) {
  __builtin_amdgcn_global_load_lds(
      (const __attribute__((address_space(1))) unsigned int*)(const void*)g,
      (__attribute__((address_space(3))) unsigned int*)(void*)l, 16, 0, 0);
}

__device__ inline float ucoef(int abit, int k, int jbit, float alpha) {
  if (abit == 0) return (k == 0) ? (jbit ? alpha : 1.f - alpha) : (jbit ? 1.f : 0.f);
  return (k == 2) ? (jbit ? 1.f - alpha : alpha) : (jbit ? 0.f : 1.f);
}

// xT2: 4 regions (16-ch groups), each 32768 sp * 32 B + 128 B zero tail.
#define XREG_USH 524352
#define XREG_B 1048704
#define XZERO_B 1048576u

// ---------------- K0: all preprocessing in one kernel (2049 blocks) ---------
__global__ void k_prep(const float* __restrict__ x, unsigned short* __restrict__ xT2,
                       const float* __restrict__ w_def, const float* __restrict__ bn1_g,
                       const float* __restrict__ bn1_v, unsigned short* __restrict__ W_sw,
                       const float* __restrict__ w_comb, const float* __restrict__ b_comb,
                       const float* __restrict__ bn2_g, const float* __restrict__ bn2_b,
                       const float* __restrict__ bn2_m, const float* __restrict__ bn2_v,
                       const float* __restrict__ b_def, const float* __restrict__ bn1_b,
                       const float* __restrict__ bn1_m, unsigned short* __restrict__ W2_sw,
                       float* __restrict__ bias1, float* __restrict__ bias2) {
  __shared__ unsigned short t[64][65];
  int bid = blockIdx.x;
  if (bid < 512) {
    int s0 = bid * 64;
    int lane = threadIdx.x & 63;
    int grp = threadIdx.x >> 6;
#pragma unroll
    for (int c = grp; c < 64; c += 4)
      t[c][lane] = f2bf(x[c * 32768 + s0 + lane]);
    __syncthreads();
    // coalesced writes: wave grp owns region grp; lane = sl*16 + e ->
    // each iteration stores one contiguous 128-B line.
    int e = lane & 15, sl = lane >> 4;
    unsigned short* dst = xT2 + (size_t)grp * XREG_USH + (size_t)s0 * 16;
#pragma unroll
    for (int sb = 0; sb < 64; sb += 4)
      dst[(sb + sl) * 16 + e] = t[grp * 16 + e][sb + sl];
  } else if (bid < 2048) {
    int e = (bid - 512) * 256 + threadIdx.x;  // < 393216
    int j = e & 7;
    int lane = (e >> 3) & 63;
    int idx = e >> 9;
    int nt = idx % 3;
    idx /= 3;
    int s = idx & 31;
    int p = idx >> 5;
    int o = lane & 31;
    int br = nt;
    int kk = 16 * s + ((lane >> 5) << 3) + j;
    int tap = kk >> 6, ch = kk & 63;
    int jz = (tap >> 2) & 1, jy = (tap >> 1) & 1, jx = tap & 1;
    int a = (p >> 2) & 1, b = (p >> 1) & 1, cp = p & 1;
    float alpha = (br == 0) ? 0.f : ((br == 1) ? 0.4f : 0.7f);
    const float* wb = w_def + (o * 64 + ch) * 27;
    float sum = 0.f;
    for (int kz = 0; kz < 3; ++kz) {
      float uz = ucoef(a, kz, jz, alpha);
      if (uz == 0.f) continue;
      for (int ky = 0; ky < 3; ++ky) {
        float uy = ucoef(b, ky, jy, alpha);
        if (uy == 0.f) continue;
        float uzy = uz * uy;
        for (int kx = 0; kx < 3; ++kx) {
          float ux = ucoef(cp, kx, jx, alpha);
          if (ux != 0.f) sum += wb[kz * 9 + ky * 3 + kx] * uzy * ux;
        }
      }
    }
    float s1 = bn1_g[o] * rsqrtf(bn1_v[o] + 1e-5f);
    W_sw[e] = f2bf(sum * s1);
  } else {
    int tid = threadIdx.x;
    for (int e = tid; e < 3072; e += 256) {
      int j = e & 7;
      int lane = (e >> 3) & 63;
      int s2 = e >> 9;
      int n = lane & 31;
      int k = 16 * s2 + ((lane >> 5) << 3) + j;
      float sc2 = bn2_g[n] * rsqrtf(bn2_v[n] + 1e-5f);
      W2_sw[e] = f2bf(w_comb[n * 96 + k] * sc2);
    }
    {
      int q = tid >> 6, e2 = tid & 63;
      xT2[q * XREG_USH + 524288 + e2] = 0;
    }
    if (tid < 32) {
      float s1 = bn1_g[tid] * rsqrtf(bn1_v[tid] + 1e-5f);
      bias1[tid] = (b_def[tid] - bn1_m[tid]) * s1 + bn1_b[tid];
      float s2 = bn2_g[tid] * rsqrtf(bn2_v[tid] + 1e-5f);
      bias2[tid] = (b_comb[tid] - bn2_m[tid]) * s2 + bn2_b[tid];
    }
  }
}

// ---------------- K1: main fused kernel -------------------------------------
// Grid 512 blocks, 512 thr (8 waves). bid: tile = bid&63 (XCD = tile%8 ->
// phase-siblings co-XCD), phase p = bid>>6 (a,bph,cp). Tile = 8x8x8 input.
// Wave wv: zs=wv>>2, ys=wv&3. M=64/wave. acc[mt][nt] f32x16 (C^T).
__launch_bounds__(512, 2)
__global__ void k_main(const unsigned short* __restrict__ xT2,
                       const unsigned short* __restrict__ W_sw,
                       const unsigned short* __restrict__ W2_sw,
                       const float* __restrict__ bias1f,
                       const float* __restrict__ bias2f,
                       float* __restrict__ out) {
  __shared__ unsigned short wlds[49152];  // whole phase: 96 KB
  __shared__ float blds[64];              // bias1 | bias2
  int tid = threadIdx.x;
  int lane = tid & 63;
  int wv = tid >> 6;  // 0..7
  int bid = blockIdx.x;
  int tb = bid & 63;      // tile (XCD = tb%8)
  int p = bid >> 6;       // phase 0..7
  int cp = p & 1, bph = (p >> 1) & 1, a = p >> 2;
  int tx = tb & 3, ty = (tb >> 2) & 3, tz = tb >> 4;  // 4x4x4 tiles of 8^3
  int i0 = tz * 8, j0 = ty * 8, k0 = tx * 8;

  const unsigned short* gph = W_sw + (size_t)p * 49152;

  // ---- prologue: stage taps 0-3 (48 KB, 6 instr/wave) + biases ----
  {
    const unsigned short* g = gph + wv * 3072 + lane * 8;
    unsigned short* l = wlds + wv * 3072;
#pragma unroll
    for (int k = 0; k < 6; ++k) gload16(g + k * 512, l + k * 512);
  }
  if (tid < 32) {
    blds[tid] = bias1f[tid];
    blds[32 + tid] = bias2f[tid];
  }

  int m = lane & 31, h = lane >> 5;
  int ax = m & 7, ay = (m >> 3) & 1, az = m >> 4;
  int zs = wv >> 2, ys = wv & 3;
  int zin0 = i0 + 4 * zs + az;  // + 2*mt
  int yin = j0 + 2 * ys + ay;
  const char* xb0 = (const char*)xT2 + (h << 4);

  // x loader: tap -> 8 uint4 (mt-major: dst[mt*4+q])
  auto ldx = [&](int tap, uint4* dst) {
    int jz = (tap >> 2) & 1, jy = (tap >> 1) & 1, jx = tap & 1;
    int gz0 = zin0 + a - 1 + jz;
    int gy = yin + bph - 1 + jy;
    int gx = k0 + ax + cp - 1 + jx;
    bool okyx = ((unsigned)gy < 32u) && ((unsigned)gx < 32u);
#pragma unroll
    for (int mt = 0; mt < 2; ++mt) {
      int gz = gz0 + 2 * mt;
      bool ok = okyx && ((unsigned)gz < 32u);
      unsigned off = (unsigned)(((gz * 32 + gy) * 32 + gx) * 32);
      unsigned xo = ok ? off : XZERO_B;
#pragma unroll
      for (int q = 0; q < 4; ++q)
        dst[mt * 4 + q] = *(const uint4*)(xb0 + q * XREG_B + xo);
    }
  };

  uint4 xA[8], xB[8];
  ldx(0, xA);       // tap-0 x in flight during the first-half drain
  __syncthreads();  // taps 0-3 resident

  // issue taps 4-7 stage NOW; it flies under taps 0-3's MFMA clusters
  {
    const unsigned short* g = gph + 24576 + wv * 3072 + lane * 8;
    unsigned short* l = wlds + 24576 + wv * 3072;
#pragma unroll
    for (int k = 0; k < 6; ++k) gload16(g + k * 512, l + k * 512);
  }

  f32x16 acc[2][3];
#pragma unroll
  for (int mt = 0; mt < 2; ++mt)
#pragma unroll
    for (int nt = 0; nt < 3; ++nt) acc[mt][nt] = (f32x16)0.f;

  // ---- main loop: x ping-pong 1 tap ahead; one mid-barrier before tap 4 ----
#pragma unroll
  for (int tap = 0; tap < 8; ++tap) {
    if (tap == 4) {
      asm volatile("s_waitcnt vmcnt(0)" ::: "memory");  // taps 4-7 landed
      __builtin_amdgcn_s_barrier();
    }
    uint4* cur = (tap & 1) ? xB : xA;
    uint4* nxt = (tap & 1) ? xA : xB;
    if (tap < 7) ldx(tap + 1, nxt);  // issue BEFORE this tap's MFMA cluster
    const unsigned short* wfb = wlds + tap * 6144 + lane * 8;
#pragma unroll
    for (int q = 0; q < 4; ++q) {  // s = 4*tap + q
      bf16x8 a0 = bc16(cur[q]);
      bf16x8 a1 = bc16(cur[4 + q]);
      const unsigned short* wf = wfb + q * 1536;
      bf16x8 bb0 = bc16(*(const uint4*)(wf));
      bf16x8 bb1 = bc16(*(const uint4*)(wf + 512));
      bf16x8 bb2 = bc16(*(const uint4*)(wf + 1024));
      __builtin_amdgcn_s_setprio(1);
      acc[0][0] = __builtin_amdgcn_mfma_f32_32x32x16_bf16(bb0, a0, acc[0][0], 0, 0, 0);
      acc[1][0] = __builtin_amdgcn_mfma_f32_32x32x16_bf16(bb0, a1, acc[1][0], 0, 0, 0);
      acc[0][1] = __builtin_amdgcn_mfma_f32_32x32x16_bf16(bb1, a0, acc[0][1], 0, 0, 0);
      acc[1][1] = __builtin_amdgcn_mfma_f32_32x32x16_bf16(bb1, a1, acc[1][1], 0, 0, 0);
      acc[0][2] = __builtin_amdgcn_mfma_f32_32x32x16_bf16(bb2, a0, acc[0][2], 0, 0, 0);
      acc[1][2] = __builtin_amdgcn_mfma_f32_32x32x16_bf16(bb2, a1, acc[1][2], 0, 0, 0);
      __builtin_amdgcn_s_setprio(0);
    }
  }

  // ---- epilogue: BN1+ReLU, cvt_pk+permlane relayout, combine, BN2+ReLU,
  //      scalar float stores (phase-exclusive output positions) ----
  const uint4* w2q = (const uint4*)W2_sw + lane;
#pragma unroll
  for (int mt = 0; mt < 2; ++mt) {
    f32x16 acc2 = (f32x16)0.f;
#pragma unroll
    for (int nt = 0; nt < 3; ++nt) {
      unsigned ww[8];
#pragma unroll
      for (int qc = 0; qc < 8; ++qc) {
        int q = qc >> 1, c2 = qc & 1;
        int r0 = 4 * q + 2 * c2;
        int row = (r0 & 3) + ((r0 >> 2) << 3) + (h << 2);
        float lo = fmaxf(acc[mt][nt][r0] + blds[row], 0.f);
        float hi = fmaxf(acc[mt][nt][r0 + 1] + blds[row + 1], 0.f);
        ww[2 * q + c2] = cvtpk(lo, hi);
      }
      plswap(ww[0], ww[2]);
      plswap(ww[1], ww[3]);
      plswap(ww[4], ww[6]);
      plswap(ww[5], ww[7]);
      uint4 frA = make_uint4(ww[0], ww[1], ww[2], ww[3]);
      uint4 frB = make_uint4(ww[4], ww[5], ww[6], ww[7]);
      acc2 = __builtin_amdgcn_mfma_f32_32x32x16_bf16(bc16(w2q[(2 * nt) * 64]),
                                                     bc16(frA), acc2, 0, 0, 0);
      acc2 = __builtin_amdgcn_mfma_f32_32x32x16_bf16(bc16(w2q[(2 * nt + 1) * 64]),
                                                     bc16(frB), acc2, 0, 0, 0);
    }
    int Z = 2 * (zin0 + 2 * mt) + a;
    int Y = 2 * yin + bph;
    int X = 2 * (k0 + ax) + cp;
    size_t sb = ((size_t)Z << 12) + (Y << 6) + X;
#pragma unroll
    for (int r = 0; r < 16; ++r) {
      int ch = (r & 3) + ((r >> 2) << 3) + (h << 2);
      out[((size_t)ch << 18) + sb] = fmaxf(acc2[r] + blds[32 + ch], 0.f);
    }
  }
}

// ---------------------------------------------------------------------------
extern "C" void kernel_launch(void* const* d_in, const int* in_sizes, int n_in,
                              void* d_out, int out_size, void* d_ws, size_t ws_size,
                              hipStream_t stream) {
  (void)in_sizes; (void)n_in; (void)out_size; (void)ws_size;
  const float* x      = (const float*)d_in[0];
  const float* w_def  = (const float*)d_in[1];
  const float* b_def  = (const float*)d_in[2];
  const float* bn1_g  = (const float*)d_in[3];
  const float* bn1_b  = (const float*)d_in[4];
  const float* bn1_m  = (const float*)d_in[5];
  const float* bn1_v  = (const float*)d_in[6];
  const float* w_comb = (const float*)d_in[7];
  const float* b_comb = (const float*)d_in[8];
  const float* bn2_g  = (const float*)d_in[9];
  const float* bn2_b  = (const float*)d_in[10];
  const float* bn2_m  = (const float*)d_in[11];
  const float* bn2_v  = (const float*)d_in[12];

  char* ws = (char*)d_ws;
  unsigned short* xT2  = (unsigned short*)(ws);             // 4,194,816 B
  unsigned short* W_sw = (unsigned short*)(ws + 4194816);   //   786,432 B
  unsigned short* W2sw = (unsigned short*)(ws + 4981248);   //     6,144 B
  float* bias1 = (float*)(ws + 4987392);                    //       128 B
  float* bias2 = (float*)(ws + 4987520);                    //       128 B
  float* out = (float*)d_out;

  hipLaunchKernelGGL(k_prep, dim3(2049), dim3(256), 0, stream,
                     x, xT2, w_def, bn1_g, bn1_v, W_sw,
                     w_comb, b_comb, bn2_g, bn2_b, bn2_m, bn2_v,
                     b_def, bn1_b, bn1_m, W2sw, bias1, bias2);
  hipLaunchKernelGGL(k_main, dim3(512), dim3(512), 0, stream,
                     xT2, W_sw, W2sw, bias1, bias2, out);
}

// Round 20
// 52.795 us; speedup vs baseline: 1.0575x; 1.0575x over previous
//
#include <hip/hip_runtime.h>

// ---------------------------------------------------------------------------
// UpThreeOffsetsConvShareWeights FINAL (= v12, session-best at 52.65 us).
//
// Algebra: separable deform offsets -> per-phase 2x2x2-tap conv == GEMM
// M=spatial x N=96 x K=512; fused K=96 combine GEMM. C^T convention
// (mfma(W_frag, x_frag), lane&31 = spatial col), 32x32x16 MFMA, v5-proven
// W_sw/W2_sw layouts, xT[sp][64] staging with rotated xt LDS tile,
// cvt_pk+permlane epilogue, full-line float2 stores (cp paired in-block).
// Schedule: depth-2 counted-vmcnt 3-slot weight ring (1-tap 12KB chunks).
//
// Session summary (19 variants): k_main plateaus at 42-50us with no pipe
// >25% (MFMA floor ~11us, HBM ~13%) at 2 waves/SIMD -- an issue/latency
// limit. Biggest single lever found: removing in-loop syncs (v16, 50->42
// k_main), but its family's totals did not beat this kernel's 52.65us.
// This file is the best-measured artifact, resubmitted byte-identical.
// ---------------------------------------------------------------------------

typedef __bf16 bf16x8 __attribute__((ext_vector_type(8)));
typedef float f32x16 __attribute__((ext_vector_type(16)));
typedef unsigned u32x2 __attribute__((ext_vector_type(2)));

__device__ inline unsigned short f2bf(float f) {
  unsigned int u = __float_as_uint(f);
  u += 0x7FFFu + ((u >> 16) & 1u);
  return (unsigned short)(u >> 16);
}

__device__ inline bf16x8 bc16(uint4 v) { return __builtin_bit_cast(bf16x8, v); }

__device__ inline unsigned cvtpk(float lo, float hi) {
  unsigned r;
  asm("v_cvt_pk_bf16_f32 %0, %1, %2" : "=v"(r) : "v"(lo), "v"(hi));
  return r;
}

__device__ inline void plswap(unsigned& a, unsigned& b) {
  u32x2 r = __builtin_amdgcn_permlane32_swap(a, b, false, false);
  a = r.x;
  b = r.y;
}

__device__ inline void gload16(const unsigned short* g, unsigned short* l) {
  __builtin_amdgcn_global_load_lds(
      (const __attribute__((address_space(1))) unsigned int*)(const void*)g,
      (__attribute__((address_space(3))) unsigned int*)(void*)l, 16, 0, 0);
}

__device__ inline float ucoef(int abit, int k, int jbit, float alpha) {
  if (abit == 0) return (k == 0) ? (jbit ? alpha : 1.f - alpha) : (jbit ? 1.f : 0.f);
  return (k == 2) ? (jbit ? 1.f - alpha : alpha) : (jbit ? 0.f : 1.f);
}

// ---------------- K0: all preprocessing in one kernel (2049 blocks) ---------
__global__ void k_prep(const float* __restrict__ x, unsigned short* __restrict__ xT,
                       const float* __restrict__ w_def, const float* __restrict__ bn1_g,
                       const float* __restrict__ bn1_v, unsigned short* __restrict__ W_sw,
                       const float* __restrict__ w_comb, const float* __restrict__ b_comb,
                       const float* __restrict__ bn2_g, const float* __restrict__ bn2_b,
                       const float* __restrict__ bn2_m, const float* __restrict__ bn2_v,
                       const float* __restrict__ b_def, const float* __restrict__ bn1_b,
                       const float* __restrict__ bn1_m, unsigned short* __restrict__ W2_sw,
                       float* __restrict__ bias1, float* __restrict__ bias2) {
  __shared__ unsigned short t[64][65];
  int bid = blockIdx.x;
  if (bid < 512) {
    int s0 = bid * 64;
    int lane = threadIdx.x & 63;
    int grp = threadIdx.x >> 6;
#pragma unroll
    for (int c = grp; c < 64; c += 4)
      t[c][lane] = f2bf(x[c * 32768 + s0 + lane]);
    __syncthreads();
#pragma unroll
    for (int s = grp; s < 64; s += 4)
      xT[(size_t)(s0 + s) * 64 + lane] = t[lane][s];
  } else if (bid < 2048) {
    int e = (bid - 512) * 256 + threadIdx.x;  // < 393216
    int j = e & 7;
    int lane = (e >> 3) & 63;
    int idx = e >> 9;
    int nt = idx % 3;
    idx /= 3;
    int s = idx & 31;
    int p = idx >> 5;
    int o = lane & 31;
    int br = nt;
    int kk = 16 * s + ((lane >> 5) << 3) + j;
    int tap = kk >> 6, ch = kk & 63;
    int jz = (tap >> 2) & 1, jy = (tap >> 1) & 1, jx = tap & 1;
    int a = (p >> 2) & 1, b = (p >> 1) & 1, cp = p & 1;
    float alpha = (br == 0) ? 0.f : ((br == 1) ? 0.4f : 0.7f);
    const float* wb = w_def + (o * 64 + ch) * 27;
    float sum = 0.f;
    for (int kz = 0; kz < 3; ++kz) {
      float uz = ucoef(a, kz, jz, alpha);
      if (uz == 0.f) continue;
      for (int ky = 0; ky < 3; ++ky) {
        float uy = ucoef(b, ky, jy, alpha);
        if (uy == 0.f) continue;
        float uzy = uz * uy;
        for (int kx = 0; kx < 3; ++kx) {
          float ux = ucoef(cp, kx, jx, alpha);
          if (ux != 0.f) sum += wb[kz * 9 + ky * 3 + kx] * uzy * ux;
        }
      }
    }
    float s1 = bn1_g[o] * rsqrtf(bn1_v[o] + 1e-5f);
    W_sw[e] = f2bf(sum * s1);
  } else {
    int tid = threadIdx.x;
    for (int e = tid; e < 3072; e += 256) {
      int j = e & 7;
      int lane = (e >> 3) & 63;
      int s2 = e >> 9;
      int n = lane & 31;
      int k = 16 * s2 + ((lane >> 5) << 3) + j;
      float sc2 = bn2_g[n] * rsqrtf(bn2_v[n] + 1e-5f);
      W2_sw[e] = f2bf(w_comb[n * 96 + k] * sc2);
    }
    if (tid < 32) {
      float s1 = bn1_g[tid] * rsqrtf(bn1_v[tid] + 1e-5f);
      bias1[tid] = (b_def[tid] - bn1_m[tid]) * s1 + bn1_b[tid];
      float s2 = bn2_g[tid] * rsqrtf(bn2_v[tid] + 1e-5f);
      bias2[tid] = (b_comb[tid] - bn2_m[tid]) * s2 + bn2_b[tid];
    }
  }
}

// ---------------- K1: main fused kernel -------------------------------------
// Grid 256 blocks (1/CU), 512 thr (8 waves). bid -> (a,bph) + 8x8x8 tile.
// Wave wv: zs=wv>>2, ys=wv&3. Per wave M=64 (2 mt x 32 m), cp = chunk>>3.
__launch_bounds__(512, 2)
__global__ void k_main(const unsigned short* __restrict__ xT,
                       const unsigned short* __restrict__ W_sw,
                       const unsigned short* __restrict__ W2_sw,
                       const float* __restrict__ bias1f,
                       const float* __restrict__ bias2f,
                       float* __restrict__ out) {
  __shared__ unsigned short xt[51840];       // 9*9*10 rows * 64 ch (101.25 KB)
  __shared__ unsigned short wring[3][6144];  // 3 slots * 12 KB (1 tap each)
  __shared__ float blds[64];                 // bias1 | bias2 tables
  int tid = threadIdx.x;
  int lane = tid & 63;
  int wv = tid >> 6;
  int bid = blockIdx.x;
  int bph = bid & 1, a = (bid >> 1) & 1;
  int tb = bid >> 2;
  int tx = tb & 3, ty = (tb >> 2) & 3, tz = tb >> 4;
  int i0 = tz * 8, j0 = ty * 8, k0 = tx * 8;

  // ---- stage xt (halo 1; z-origin shifted by a, y-origin by bph) ----
  for (int t2 = tid; t2 < 6480; t2 += 512) {  // 810 rows * 8 ch-blocks
    int cblk = t2 & 7;
    int r = t2 >> 3;  // row = (zrel*9 + yrel)*10 + xrel
    int xrel = r % 10;
    int zy = r / 10;
    int yrel = zy % 9;
    int zrel = zy / 9;
    int gz = i0 + a - 1 + zrel, gy = j0 + bph - 1 + yrel, gx = k0 - 1 + xrel;
    uint4 v = make_uint4(0u, 0u, 0u, 0u);
    if ((unsigned)gz < 32u && (unsigned)gy < 32u && (unsigned)gx < 32u)
      v = *(const uint4*)(xT + ((((gz * 32 + gy) * 32 + gx) << 6) + (cblk << 3)));
    *(uint4*)(xt + ((r << 6) + (((cblk + r) << 3) & 63))) = v;
  }
  if (tid < 32) {
    blds[tid] = bias1f[tid];
    blds[32 + tid] = bias2f[tid];
  }

  // combine weights in registers (loaded before the big sync)
  bf16x8 b2f[6];
  const uint4* w2q = (const uint4*)W2_sw;
#pragma unroll
  for (int s2 = 0; s2 < 6; ++s2) b2f[s2] = bc16(w2q[s2 * 64 + lane]);
  __syncthreads();  // drains ALL pre-loop VMEM: vmcnt==0 from here

  int h = lane >> 5, h8 = h << 3;
  int m = lane & 31;
  int ax = m & 7, ay = (m >> 3) & 1, az = m >> 4;
  int zs = wv >> 2, ys = wv & 3;
  int dz0 = 4 * zs + az;  // + 2*mt
  int dy = 2 * ys + ay;
  int p0 = (a << 2) | (bph << 1);

  // chunk c (0..15): phase p0|(c>>3), tap c&7 (12288 B). Waves 0-5 stage
  // 2048 B each as 2 x width-16 wave-instructions; waves 6-7 idle (their
  // vmcnt is trivially satisfied; the barrier hands them the data).
  auto stage = [&](int c, int slot) {
    if (wv < 6) {
      int pn = p0 | (c >> 3);
      const unsigned short* g =
          W_sw + (size_t)pn * 49152 + (c & 7) * 6144 + wv * 1024 + lane * 8;
      unsigned short* l = &wring[slot][wv * 1024];
      gload16(g, l);
      gload16(g + 512, l + 512);
    }
  };

  stage(0, 0);  // prologue: 2 chunks in flight
  stage(1, 1);

  f32x16 osv0, osv1;  // cp=0 results, held across cp=1
  f32x16 acc[2][3];
#pragma unroll
  for (int mt = 0; mt < 2; ++mt)
#pragma unroll
    for (int nt = 0; nt < 3; ++nt) acc[mt][nt] = (f32x16)0.f;

  for (int c = 0; c < 16; ++c) {
    // counted wait: own chunk-c loads landed; chunk c+1 stays IN FLIGHT.
    if (c < 15) {
      asm volatile("s_waitcnt vmcnt(2)" ::: "memory");
    } else {
      asm volatile("s_waitcnt vmcnt(0)" ::: "memory");
    }
    __builtin_amdgcn_s_barrier();  // all waves' chunk-c parts visible
    __builtin_amdgcn_sched_barrier(0);
    if (c < 14) stage(c + 2, (c + 2) % 3);  // overwrites chunk c-1's slot: safe
    __builtin_amdgcn_sched_barrier(0);

    int cp = c >> 3, t8 = c & 7;
    int jz = (t8 >> 2) & 1, jy = (t8 >> 1) & 1, jx = t8 & 1;
    int row0 = ((dz0 + jz) * 9 + (dy + jy)) * 10 + (ax + cp + jx);
    int row1 = row0 + 180;  // mt=1: z += 2
    const unsigned short* wfb = &wring[c % 3][lane * 8];
#pragma unroll
    for (int q = 0; q < 4; ++q) {  // s = 4*tap + q
      int c0 = (q << 4) + h8;
      int e0 = (row0 << 6) + ((c0 + (row0 << 3)) & 63);
      int e1 = (row1 << 6) + ((c0 + (row1 << 3)) & 63);
      bf16x8 a0 = bc16(*(const uint4*)(xt + e0));
      bf16x8 a1 = bc16(*(const uint4*)(xt + e1));
      const unsigned short* wf = wfb + q * 1536;
      bf16x8 bb0 = bc16(*(const uint4*)(wf));
      bf16x8 bb1 = bc16(*(const uint4*)(wf + 512));
      bf16x8 bb2 = bc16(*(const uint4*)(wf + 1024));
      __builtin_amdgcn_s_setprio(1);
      acc[0][0] = __builtin_amdgcn_mfma_f32_32x32x16_bf16(bb0, a0, acc[0][0], 0, 0, 0);
      acc[1][0] = __builtin_amdgcn_mfma_f32_32x32x16_bf16(bb0, a1, acc[1][0], 0, 0, 0);
      acc[0][1] = __builtin_amdgcn_mfma_f32_32x32x16_bf16(bb1, a0, acc[0][1], 0, 0, 0);
      acc[1][1] = __builtin_amdgcn_mfma_f32_32x32x16_bf16(bb1, a1, acc[1][1], 0, 0, 0);
      acc[0][2] = __builtin_amdgcn_mfma_f32_32x32x16_bf16(bb2, a0, acc[0][2], 0, 0, 0);
      acc[1][2] = __builtin_amdgcn_mfma_f32_32x32x16_bf16(bb2, a1, acc[1][2], 0, 0, 0);
      __builtin_amdgcn_s_setprio(0);
    }

    if (c == 7) {
      // ---- cp=0 epilogue: BN1+ReLU, in-reg relayout, combine, BN2+ReLU ----
      // (no VMEM: keeps the counted-ring discipline intact)
#pragma unroll
      for (int mt = 0; mt < 2; ++mt) {
        uint4 fr[6];
#pragma unroll
        for (int nt = 0; nt < 3; ++nt) {
          unsigned ww[8];
#pragma unroll
          for (int qc = 0; qc < 8; ++qc) {
            int q = qc >> 1, c2 = qc & 1;
            int r0 = 4 * q + 2 * c2;
            int row = (r0 & 3) + ((r0 >> 2) << 3) + (h << 2);
            float lo = fmaxf(acc[mt][nt][r0] + blds[row], 0.f);
            float hi = fmaxf(acc[mt][nt][r0 + 1] + blds[row + 1], 0.f);
            ww[2 * q + c2] = cvtpk(lo, hi);
          }
          plswap(ww[0], ww[2]);
          plswap(ww[1], ww[3]);
          plswap(ww[4], ww[6]);
          plswap(ww[5], ww[7]);
          fr[2 * nt] = make_uint4(ww[0], ww[1], ww[2], ww[3]);
          fr[2 * nt + 1] = make_uint4(ww[4], ww[5], ww[6], ww[7]);
        }
        f32x16 acc2 = (f32x16)0.f;
#pragma unroll
        for (int s2 = 0; s2 < 6; ++s2)
          acc2 = __builtin_amdgcn_mfma_f32_32x32x16_bf16(b2f[s2], bc16(fr[s2]), acc2, 0, 0, 0);
        f32x16 ov;
#pragma unroll
        for (int r = 0; r < 16; ++r) {
          int row = (r & 3) + ((r >> 2) << 3) + (h << 2);
          ov[r] = fmaxf(acc2[r] + blds[32 + row], 0.f);
        }
        if (mt == 0) osv0 = ov; else osv1 = ov;
#pragma unroll
        for (int nt = 0; nt < 3; ++nt) acc[mt][nt] = (f32x16)0.f;
      }
    }
  }

  // ---- cp=1 epilogue: same pipeline + full-line float2 stores ----
#pragma unroll
  for (int mt = 0; mt < 2; ++mt) {
    uint4 fr[6];
#pragma unroll
    for (int nt = 0; nt < 3; ++nt) {
      unsigned ww[8];
#pragma unroll
      for (int qc = 0; qc < 8; ++qc) {
        int q = qc >> 1, c2 = qc & 1;
        int r0 = 4 * q + 2 * c2;
        int row = (r0 & 3) + ((r0 >> 2) << 3) + (h << 2);
        float lo = fmaxf(acc[mt][nt][r0] + blds[row], 0.f);
        float hi = fmaxf(acc[mt][nt][r0 + 1] + blds[row + 1], 0.f);
        ww[2 * q + c2] = cvtpk(lo, hi);
      }
      plswap(ww[0], ww[2]);
      plswap(ww[1], ww[3]);
      plswap(ww[4], ww[6]);
      plswap(ww[5], ww[7]);
      fr[2 * nt] = make_uint4(ww[0], ww[1], ww[2], ww[3]);
      fr[2 * nt + 1] = make_uint4(ww[4], ww[5], ww[6], ww[7]);
    }
    f32x16 acc2 = (f32x16)0.f;
#pragma unroll
    for (int s2 = 0; s2 < 6; ++s2)
      acc2 = __builtin_amdgcn_mfma_f32_32x32x16_bf16(b2f[s2], bc16(fr[s2]), acc2, 0, 0, 0);
    f32x16 prev = (mt == 0) ? osv0 : osv1;
    int Z = 2 * (i0 + 4 * zs + 2 * mt + az) + a;
    int Y = 2 * (j0 + dy) + bph;
    float2* o2 = (float2*)out;
#pragma unroll
    for (int r = 0; r < 16; ++r) {
      int ch = (r & 3) + ((r >> 2) << 3) + (h << 2);
      float v1 = fmaxf(acc2[r] + blds[32 + ch], 0.f);
      o2[((size_t)ch << 17) + ((size_t)Z << 11) + (Y << 5) + (k0 + ax)] =
          make_float2(prev[r], v1);
    }
  }
}

// ---------------------------------------------------------------------------
extern "C" void kernel_launch(void* const* d_in, const int* in_sizes, int n_in,
                              void* d_out, int out_size, void* d_ws, size_t ws_size,
                              hipStream_t stream) {
  (void)in_sizes; (void)n_in; (void)out_size; (void)ws_size;
  const float* x      = (const float*)d_in[0];
  const float* w_def  = (const float*)d_in[1];
  const float* b_def  = (const float*)d_in[2];
  const float* bn1_g  = (const float*)d_in[3];
  const float* bn1_b  = (const float*)d_in[4];
  const float* bn1_m  = (const float*)d_in[5];
  const float* bn1_v  = (const float*)d_in[6];
  const float* w_comb = (const float*)d_in[7];
  const float* b_comb = (const float*)d_in[8];
  const float* bn2_g  = (const float*)d_in[9];
  const float* bn2_b  = (const float*)d_in[10];
  const float* bn2_m  = (const float*)d_in[11];
  const float* bn2_v  = (const float*)d_in[12];

  char* ws = (char*)d_ws;
  unsigned short* xT   = (unsigned short*)(ws);             // 4,194,304 B
  unsigned short* W_sw = (unsigned short*)(ws + 4194304);   //   786,432 B
  unsigned short* W2sw = (unsigned short*)(ws + 4980736);   //     6,144 B
  float* bias1 = (float*)(ws + 4986880);                    //       128 B
  float* bias2 = (float*)(ws + 4987008);                    //       128 B
  float* out = (float*)d_out;

  hipLaunchKernelGGL(k_prep, dim3(2049), dim3(256), 0, stream,
                     x, xT, w_def, bn1_g, bn1_v, W_sw,
                     w_comb, b_comb, bn2_g, bn2_b, bn2_m, bn2_v,
                     b_def, bn1_b, bn1_m, W2sw, bias1, bias2);
  hipLaunchKernelGGL(k_main, dim3(256), dim3(512), 0, stream,
                     xT, W_sw, W2sw, bias1, bias2, out);
}